// Round 7
// baseline (5767.986 us; speedup 1.0000x reference)
//
#include <hip/hip_runtime.h>
#include <cstdint>
#include <cstddef>

// ---------------- problem dims ----------------
#define TSTEPS 256
#define BATCH  64
#define OBSD   512
#define HIDD   1024
#define NACT   128
#define TOK    (TSTEPS*BATCH)   // 16384

// fp32 output element offsets
static constexpr size_t O_PROBS = 0;
static constexpr size_t O_LOGPA = (size_t)TOK * NACT;
static constexpr size_t O_ENT   = O_LOGPA + TOK;
static constexpr size_t O_VAL   = O_ENT + TOK;
static constexpr size_t O_HT    = O_VAL + TOK;
static constexpr size_t O_CT    = O_HT + (size_t)BATCH * HIDD;

// bf16 weight/activation pool offsets (elements)
static constexpr size_t OX     = 0;
static constexpr size_t OCOVH  = 8388608;
static constexpr size_t OSNW1  = 10485760;
static constexpr size_t OSNW2  = 11010048;
static constexpr size_t OWIH   = 12058624;
static constexpr size_t OWHH   = 16252928;
static constexpr size_t OACW1  = 20447232;   // ac|cw|cr contiguous -> one N=3072 GEMM
static constexpr size_t OCWW1  = 21495808;
static constexpr size_t OCRW1  = 22544384;
static constexpr size_t OACW2  = 23592960;
static constexpr size_t OCWW2  = 23724032;
static constexpr size_t OCOVW1 = 23855104;
static constexpr size_t OCOVW2 = 23986176;
static constexpr size_t OCRW2  = 24117248;
static constexpr size_t WBUFSZ = 24118272;

using bf16x8 = __attribute__((ext_vector_type(8))) short;
using f32x4  = __attribute__((ext_vector_type(4))) float;

// ---------------- device buffers (all resolved in device code) ----------------
__device__ __align__(16) unsigned short g_wbuf[WBUFSZ];
__device__ __align__(16) unsigned short g_hid1[(size_t)TOK*HIDD];
__device__ __align__(16) unsigned short g_hid [(size_t)TOK*HIDD];
__device__ __align__(16) float          g_xgf [(size_t)TOK*4*HIDD];
__device__ __align__(16) unsigned short g_hid2[(size_t)64*TOK*16];   // blocked hidden [colblk][token][16]
__device__ __align__(16) unsigned short g_t3[(size_t)TOK*3*HIDD];    // [TOK][3072] ac|cw|cr
__device__ __align__(16) unsigned short g_aco[(size_t)TOK*NACT];
__device__ __align__(16) unsigned short g_cwo[(size_t)TOK*NACT];
__device__ __align__(16) unsigned short g_covo[(size_t)TOK*NACT];
// blocked h ping-pong. fast layout: [parity][group(8)][shard(64)][row(8)][col(16)]
//                      safe layout: [parity][group(4)][shard(64)][row(16)][col(16)]
__device__ __align__(16) unsigned short g_hp2[2*64*1024];
__device__ float g_ht[BATCH*HIDD];
__device__ float g_ct[BATCH*HIDD];
__device__ int g_isf32;
// flag-based step barriers. g_flags: fast kernel (512 WGs, [grp][shrd]).
// g_flags2: safe kernel (256 WGs). Disjoint arrays -> an aborted fast run can
// never confuse the safe protocol. Monotonic epochs via g_fepoch (+512/launch).
__device__ unsigned g_flags[512];
__device__ unsigned g_flags2[256];
__device__ unsigned g_xcc[512];
__device__ unsigned g_fepoch;
// fast-kernel liveness state (zeroed each launch by detect_dtype)
__device__ unsigned g_cnt;     // rendezvous count-in
__device__ unsigned g_abort;   // chip-wide abort latch
__device__ unsigned g_done;    // completion count (512 == fast path did the scan)

__device__ __forceinline__ unsigned short* dev_buf(int id){
  switch(id){
    case 1:  return g_hid1;
    case 2:  return g_hid;
    case 3:  return g_hid2;
    case 4:  return g_t3;
    case 5:  return g_aco;
    case 6:  return g_cwo;
    case 7:  return g_covo;
    case 8:  return (unsigned short*)g_xgf;
    case 9:  return g_t3 + 1024;          // cw slice (row-interleaved, lda 3072)
    case 10: return g_t3 + 2048;          // cr slice
    case 11: return g_wbuf + OX;
    case 12: return g_wbuf + OCOVH;
    case 13: return g_wbuf + OSNW1;
    case 14: return g_wbuf + OSNW2;
    case 15: return g_wbuf + OWIH;
    case 16: return g_wbuf + OWHH;
    case 17: return g_wbuf + OACW1;       // 3072-row fused head weight
    case 20: return g_wbuf + OACW2;
    case 21: return g_wbuf + OCWW2;
    case 22: return g_wbuf + OCOVW1;
    case 23: return g_wbuf + OCOVW2;
    case 24: return g_wbuf + OCRW2;
    default: return nullptr;
  }
}

// ---------------- helpers ----------------
__device__ __forceinline__ float b2f(unsigned short u){
  unsigned int x = ((unsigned int)u) << 16;
  return __builtin_bit_cast(float, x);
}
__device__ __forceinline__ unsigned short f2b(float f){
  unsigned int u = __builtin_bit_cast(unsigned int, f);
  u += 0x7FFFu + ((u >> 16) & 1u);
  return (unsigned short)(u >> 16);
}
__device__ __forceinline__ float ldmix(const void* p, size_t i){
  return g_isf32 ? ((const float*)p)[i] : b2f(((const unsigned short*)p)[i]);
}
__device__ __forceinline__ float ldsel(bool f32, const void* p, size_t i){
  return f32 ? ((const float*)p)[i] : b2f(((const unsigned short*)p)[i]);
}
__device__ __forceinline__ float sigm(float x){ return 1.f/(1.f + __expf(-x)); }
__device__ __forceinline__ float tanh_f(float x){ float e = __expf(2.f*x); return 1.f - 2.f/(e + 1.f); }

// plain (L2-cached) direct-to-LDS 16B copy — GEMM staging on read-once data
__device__ __forceinline__ void gld16(const unsigned short* g, unsigned short* l){
  __builtin_amdgcn_global_load_lds(
      (__attribute__((address_space(1))) void*)(uintptr_t)g,
      (__attribute__((address_space(3))) void*)l,
      16, 0, 0);
}
// SC1 (agent-coherent) copy — bypasses per-XCD L2, reads the mall. CPol bit4.
// (Validated on-HW in rounds 2-4: correctness + FETCH_SIZE signature.)
__device__ __forceinline__ void gld16c(const unsigned short* g, unsigned short* l){
  __builtin_amdgcn_global_load_lds(
      (__attribute__((address_space(1))) void*)(uintptr_t)g,
      (__attribute__((address_space(3))) void*)l,
      16, 0, 16);
}
// SC0 (L1-bypass) copy — reads the XCD's shared L2 (sees same-XCD dirty lines).
__device__ __forceinline__ void gld16s(const unsigned short* g, unsigned short* l){
  __builtin_amdgcn_global_load_lds(
      (__attribute__((address_space(1))) void*)(uintptr_t)g,
      (__attribute__((address_space(3))) void*)l,
      16, 0, 1);
}

// path-selected 32-bit store: fast = plain volatile store (write-through L1,
// dirty in local XCD L2; compiler-tracked vmcnt so barriers drain it),
// slow = sc1 write-through (mall-visible at vmcnt-retire; R2/R3-proven).
__device__ __forceinline__ void st32p(unsigned* p, unsigned v, bool lcl){
  if (lcl) *(volatile unsigned*)p = v;
  else     __hip_atomic_store(p, v, __ATOMIC_RELAXED, __HIP_MEMORY_SCOPE_AGENT);
}
// path-selected flag poll load: fast = sc0 (L1-bypass, reads shared XCD L2),
// slow = sc1 via relaxed agent atomic (mall). "=&v" EARLY-CLOBBER is
// load-bearing (dest must not alias the 64-bit address pair in a poll loop).
__device__ __forceinline__ unsigned ld32p(const unsigned* p, bool lcl){
  unsigned f;
  if (lcl)
    asm volatile("global_load_dword %0, %1, off sc0\n\ts_waitcnt vmcnt(0)"
                 : "=&v"(f) : "v"(p) : "memory");
  else
    f = __hip_atomic_load(p, __ATOMIC_RELAXED, __HIP_MEMORY_SCOPE_AGENT);
  return f;
}

// ---------------- dtype detect (+ per-launch state reset) ----------------
__global__ __launch_bounds__(256) void detect_dtype(const unsigned short* x){
  __shared__ int cnt;
  if (threadIdx.x == 0) cnt = 0;
  __syncthreads();
  int c = 0;
  for (int i = threadIdx.x; i < 4096; i += 256){
    float f = b2f(x[2*i]);
    if (!(fabsf(f) < 1e10f)) c++;
  }
  atomicAdd(&cnt, c);
  __syncthreads();
  if (threadIdx.x == 0){
    g_isf32 = (cnt > 64) ? 1 : 0;
    g_fepoch += 512;   // > max per-launch flag advance, keeps epochs monotonic
    g_cnt = 0; g_abort = 0; g_done = 0;
  }
}

// ---------------- convert 14 arrays into g_wbuf (bf16) ----------------
__global__ __launch_bounds__(256) void cvt_all(
    const void* s0, const void* s1, const void* s2, const void* s3,
    const void* s4, const void* s5, const void* s6, const void* s7,
    const void* s8, const void* s9, const void* s10, const void* s11,
    const void* s12, const void* s13)
{
  const void* src; size_t off; int n;
  switch (blockIdx.y){
    case 0:  src=s0;  off=OX;     n=TOK*OBSD;  break;
    case 1:  src=s1;  off=OCOVH;  n=TOK*NACT;  break;
    case 2:  src=s2;  off=OSNW1;  n=HIDD*OBSD; break;
    case 3:  src=s3;  off=OSNW2;  n=HIDD*HIDD; break;
    case 4:  src=s4;  off=OWIH;   n=4*HIDD*HIDD; break;
    case 5:  src=s5;  off=OWHH;   n=4*HIDD*HIDD; break;
    case 6:  src=s6;  off=OACW1;  n=HIDD*HIDD; break;
    case 7:  src=s7;  off=OCWW1;  n=HIDD*HIDD; break;
    case 8:  src=s8;  off=OCRW1;  n=HIDD*HIDD; break;
    case 9:  src=s9;  off=OACW2;  n=NACT*HIDD; break;
    case 10: src=s10; off=OCWW2;  n=NACT*HIDD; break;
    case 11: src=s11; off=OCOVW1; n=HIDD*NACT; break;
    case 12: src=s12; off=OCOVW2; n=NACT*HIDD; break;
    default: src=s13; off=OCRW2;  n=HIDD;      break;
  }
  const bool f32 = (g_isf32 != 0);
  unsigned short* dst = g_wbuf + off;
  const int stride = gridDim.x * 256;
  for (int i = blockIdx.x*256 + threadIdx.x; i < n; i += stride){
    float v = f32 ? ((const float*)src)[i] : b2f(((const unsigned short*)src)[i]);
    dst[i] = f2b(v);
  }
}

// ---------------- tiled MFMA GEMM: C = act(A @ W^T + bias) ----------------
// 2-phase double-buffered; ONE vmcnt(0)+barrier per K-step. (R4-verified)
__global__ __launch_bounds__(256) void gemm_bt(
    int a_id, int lda, int ablk, int w_id, int K,
    const void* __restrict__ b1, const void* __restrict__ b2, const void* __restrict__ b3,
    int bmode, int c_id, int ldc, int act, int cmode)
{
  __shared__ unsigned short sA[2][128*32];
  __shared__ unsigned short sB[2][128*32];
  const unsigned short* A = dev_buf(a_id);
  const unsigned short* W = dev_buf(w_id);
  void* C = dev_buf(c_id);

  const int tid  = threadIdx.x;
  const int wv   = tid >> 6, ln = tid & 63;
  const int quad = ln >> 4, l16 = ln & 15;
  const long bm = (long)blockIdx.y * 128, bn = (long)blockIdx.x * 128;
  const int wr = (wv >> 1) * 64, wc = (wv & 1) * 64;

  const f32x4 zf = {0.f, 0.f, 0.f, 0.f};
  f32x4 acc[4][4];
#pragma unroll
  for (int i = 0; i < 4; i++)
#pragma unroll
    for (int j = 0; j < 4; j++) acc[i][j] = zf;

  const int srow = wv*32 + (ln >> 2);
  const int scol = (ln & 3) * 8;
  const unsigned short* gA = A + (bm + srow)*(long)lda + scol;
  const unsigned short* gB = W + (bn + srow)*(long)K   + scol;
  const int lofs = (wv*32)*32;

  auto STAGE = [&](int k0, int b){
    unsigned short* lA = &sA[b][lofs];
    unsigned short* lB = &sB[b][lofs];
    if (ablk){
      const int kk = k0 + scol;
      const long cbase = (long)(kk >> 4) * ((long)TOK*16) + (kk & 15);
      gld16(A + cbase + (bm + srow)*16,      lA);
      gld16(A + cbase + (bm + srow + 16)*16, lA + 16*32);
    } else {
      gld16(gA + k0,                lA);
      gld16(gA + k0 + 16*(long)lda, lA + 16*32);
    }
    gld16(gB + k0,               lB);
    gld16(gB + k0 + 16*(long)K,  lB + 16*32);
  };

  STAGE(0, 0);
  asm volatile("s_waitcnt vmcnt(0)" ::: "memory");
  __syncthreads();

  int cur = 0;
  for (int k0 = 0; k0 < K; k0 += 32){
    if (k0 + 32 < K) STAGE(k0 + 32, cur ^ 1);
    bf16x8 af[4], bfr[4];
#pragma unroll
    for (int i = 0; i < 4; i++) af[i]  = *(const bf16x8*)&sA[cur][(wr + 16*i + l16)*32 + quad*8];
#pragma unroll
    for (int j = 0; j < 4; j++) bfr[j] = *(const bf16x8*)&sB[cur][(wc + 16*j + l16)*32 + quad*8];
#pragma unroll
    for (int i = 0; i < 4; i++)
#pragma unroll
      for (int j = 0; j < 4; j++)
        acc[i][j] = __builtin_amdgcn_mfma_f32_16x16x32_bf16(af[i], bfr[j], acc[i][j], 0, 0, 0);
    asm volatile("s_waitcnt vmcnt(0)" ::: "memory");
    __syncthreads();
    cur ^= 1;
  }

#pragma unroll
  for (int j = 0; j < 4; j++){
    const long col = bn + wc + 16*j + l16;
    float bb;
    if (bmode){
      const void* bp = (col < 1024) ? b1 : (col < 2048) ? b2 : b3;
      bb = ldmix(bp, col & 1023);
    } else {
      bb = (b1 ? ldmix(b1, col) : 0.f) + (b2 ? ldmix(b2, col) : 0.f);
    }
#pragma unroll
    for (int i = 0; i < 4; i++){
#pragma unroll
      for (int r = 0; r < 4; r++){
        const long row = bm + wr + 16*i + quad*4 + r;
        float v = acc[i][j][r] + bb;
        if (act) v = tanh_f(v);
        if (cmode) ((float*)C)[row*(long)ldc + col] = v;
        else ((unsigned short*)C)[row*(long)ldc + col] = f2b(v);
      }
    }
  }
}

// ---------------- fused head GEMMs: aco | cwo | covo in ONE launch ----------------
__global__ __launch_bounds__(256) void gemm_heads(
    const void* __restrict__ b_ac, const void* __restrict__ b_cw,
    const void* __restrict__ b_cov)
{
  __shared__ unsigned short sA[2][128*32];
  __shared__ unsigned short sB[2][128*32];

  const int which = blockIdx.x;
  const unsigned short* A; const unsigned short* W; unsigned short* C;
  const void* bias; long lda;
  if (which == 0){ A = g_t3;        lda = 3072; W = g_wbuf + OACW2;  C = g_aco;  bias = b_ac; }
  else if (which == 1){ A = g_t3 + 1024; lda = 3072; W = g_wbuf + OCWW2;  C = g_cwo;  bias = b_cw; }
  else { A = g_hid1;      lda = 1024; W = g_wbuf + OCOVW2; C = g_covo; bias = b_cov; }
  const int K = HIDD;

  const int tid  = threadIdx.x;
  const int wv   = tid >> 6, ln = tid & 63;
  const int quad = ln >> 4, l16 = ln & 15;
  const long bm = (long)blockIdx.y * 128;
  const int wr = (wv >> 1) * 64, wc = (wv & 1) * 64;

  const f32x4 zf = {0.f, 0.f, 0.f, 0.f};
  f32x4 acc[4][4];
#pragma unroll
  for (int i = 0; i < 4; i++)
#pragma unroll
    for (int j = 0; j < 4; j++) acc[i][j] = zf;

  const int srow = wv*32 + (ln >> 2);
  const int scol = (ln & 3) * 8;
  const unsigned short* gA = A + (bm + srow)*lda + scol;
  const unsigned short* gB = W + (long)srow*K    + scol;
  const int lofs = (wv*32)*32;

  auto STAGE = [&](int k0, int b){
    unsigned short* lA = &sA[b][lofs];
    unsigned short* lB = &sB[b][lofs];
    gld16(gA + k0,            lA);
    gld16(gA + k0 + 16*lda,   lA + 16*32);
    gld16(gB + k0,            lB);
    gld16(gB + k0 + 16*K,     lB + 16*32);
  };

  STAGE(0, 0);
  asm volatile("s_waitcnt vmcnt(0)" ::: "memory");
  __syncthreads();

  int cur = 0;
  for (int k0 = 0; k0 < K; k0 += 32){
    if (k0 + 32 < K) STAGE(k0 + 32, cur ^ 1);
    bf16x8 af[4], bfr[4];
#pragma unroll
    for (int i = 0; i < 4; i++) af[i]  = *(const bf16x8*)&sA[cur][(wr + 16*i + l16)*32 + quad*8];
#pragma unroll
    for (int j = 0; j < 4; j++) bfr[j] = *(const bf16x8*)&sB[cur][(wc + 16*j + l16)*32 + quad*8];
#pragma unroll
    for (int i = 0; i < 4; i++)
#pragma unroll
      for (int j = 0; j < 4; j++)
        acc[i][j] = __builtin_amdgcn_mfma_f32_16x16x32_bf16(af[i], bfr[j], acc[i][j], 0, 0, 0);
    asm volatile("s_waitcnt vmcnt(0)" ::: "memory");
    __syncthreads();
    cur ^= 1;
  }

#pragma unroll
  for (int j = 0; j < 4; j++){
    const int col = wc + 16*j + l16;
    float bb = ldmix(bias, col);
#pragma unroll
    for (int i = 0; i < 4; i++){
#pragma unroll
      for (int r = 0; r < 4; r++){
        const long row = bm + wr + 16*i + quad*4 + r;
        C[row*(long)NACT + col] = f2b(acc[i][j][r] + bb);
      }
    }
  }
}

// ======================= FAST LSTM scan (un-hangable attempt) =======================
// 512 WGs = 8 batch-groups x 64 shards; grp = cbid&7 so each group's 64-WG
// all-to-all lands on one XCD under round-robin dispatch (runtime-verified via
// HW_REG_XCC_ID; non-local groups use the proven sc1 protocol).
// LIVENESS: (1) count-in rendezvous with timeout proves all 512 are resident
// before any protocol state is touched; (2) every spin checks g_abort+timeout
// and exits WG-uniformly at the next barrier; (3) completion counted in g_done.
// The safe kernel (below) recomputes everything unless g_done==512.
__global__ __launch_bounds__(256, 2) void lstm_scan_fast(
    const void* __restrict__ done_p,
    const void* __restrict__ h0_p,
    const void* __restrict__ c0_p)
{
  __shared__ __align__(16) unsigned short sH[8208];  // 4KB/wave staged h + zero pad
  __shared__ int s_lcl;
  __shared__ int s_st;
  __shared__ int s_abort;
  float* sPf = (float*)sH;     // slab view: wave w2 at float offset w2*1024

  const int tid  = threadIdx.x;
  const int wv   = tid >> 6, ln = tid & 63;
  const int quad = ln >> 4, l16 = ln & 15;
  const int cbid = blockIdx.x;
  const int grp  = cbid & 7;           // batch-group: rows [grp*8, +8)
  const int shrd = cbid >> 3;          // col-shard:  cols [shrd*16, +16)
  const int rr0  = grp * 8;
  const int cc0  = shrd * 16;
  const bool act = (tid < 128);        // 8 rows x 16 cols = 128 active threads
  const int row  = tid >> 4;
  const int col  = tid & 15;
  const bool isf32 = (g_isf32 != 0);
  const unsigned fbase = g_fepoch;
  const int fown = grp*64 + shrd;

  if (tid == 0){ s_abort = 0; s_st = 0; }
  if (tid < 8) sH[8192 + tid] = 0;     // zero pad rows for the 8-row A operand

  // ---- rendezvous: count in; all 512 must appear before a bounded deadline ----
  const unsigned long long t0 = __builtin_amdgcn_s_memrealtime();
  __syncthreads();
  if (tid == 0)
    __hip_atomic_fetch_add(&g_cnt, 1u, __ATOMIC_RELAXED, __HIP_MEMORY_SCOPE_AGENT);
  for (;;){
    if (tid == 0){
      unsigned c = __hip_atomic_load(&g_cnt,   __ATOMIC_RELAXED, __HIP_MEMORY_SCOPE_AGENT);
      unsigned a = __hip_atomic_load(&g_abort, __ATOMIC_RELAXED, __HIP_MEMORY_SCOPE_AGENT);
      if (c >= 512u) s_st = 1;
      else if (a || (__builtin_amdgcn_s_memrealtime() - t0) > 400000ull) s_st = 2;
    }
    __syncthreads();
    const int st = s_st;
    __syncthreads();
    if (st == 1) break;
    if (st == 2){
      if (tid == 0)
        __hip_atomic_store(&g_abort, 1u, __ATOMIC_RELAXED, __HIP_MEMORY_SCOPE_AGENT);
      return;   // nothing written yet — safe kernel will do the scan
    }
    __builtin_amdgcn_s_sleep(8);
  }

  // ---- round A: XCC-id exchange -> group-uniform locality decision ----
  unsigned myxcc;
  asm volatile("s_getreg_b32 %0, hwreg(HW_REG_XCC_ID)" : "=s"(myxcc));
  if (tid == 0)
    __hip_atomic_store(&g_xcc[fown], myxcc, __ATOMIC_RELAXED, __HIP_MEMORY_SCOPE_AGENT);
  __syncthreads();   // drains the xcc store -> mall-visible before flag
  if (tid == 0)
    __hip_atomic_store(&g_flags[fown], fbase + 1u, __ATOMIC_RELAXED, __HIP_MEMORY_SCOPE_AGENT);
  {
    const unsigned long long tp = __builtin_amdgcn_s_memrealtime();
    unsigned it = 0;
    unsigned f = __hip_atomic_load(&g_flags[grp*64 + ln], __ATOMIC_RELAXED, __HIP_MEMORY_SCOPE_AGENT);
    while (!__all((int)(f >= fbase + 1u))){
      if (((++it) & 255u) == 0u){
        unsigned a = __hip_atomic_load(&g_abort, __ATOMIC_RELAXED, __HIP_MEMORY_SCOPE_AGENT);
        if (a || (__builtin_amdgcn_s_memrealtime() - tp) > 400000ull){
          if (ln == 0) *(volatile int*)&s_abort = 1;
          break;
        }
      }
      __builtin_amdgcn_s_sleep(1);
      f = __hip_atomic_load(&g_flags[grp*64 + ln], __ATOMIC_RELAXED, __HIP_MEMORY_SCOPE_AGENT);
    }
  }
  __syncthreads();
  if (*(volatile int*)&s_abort){
    if (tid == 0)
      __hip_atomic_store(&g_abort, 1u, __ATOMIC_RELAXED, __HIP_MEMORY_SCOPE_AGENT);
    return;
  }
  asm volatile("" ::: "memory");
  if (wv == 0){
    unsigned ox = __hip_atomic_load(&g_xcc[grp*64 + ln], __ATOMIC_RELAXED, __HIP_MEMORY_SCOPE_AGENT);
    int l = __all((int)(ox == myxcc));
    if (ln == 0) s_lcl = l;
  }
  __syncthreads();
  const bool lcl = (s_lcl != 0);       // uniform across WG and (by same inputs) group

  // cell state + step-0 inputs
  float cst = 0.f, dcur = 0.f, dnxt = 0.f;
  float xgv0 = 0.f, xgv1 = 0.f, xgv2 = 0.f, xgv3 = 0.f;
  if (act){
    cst  = ldsel(isf32, c0_p, (size_t)(rr0 + row)*HIDD + cc0 + col);
    dcur = ldsel(isf32, done_p, rr0 + row);
    dnxt = ldsel(isf32, done_p, BATCH + rr0 + row);
    const float* xr = &g_xgf[(size_t)(rr0 + row)*4096 + cc0 + col];
    xgv0 = xr[0]; xgv1 = xr[1024]; xgv2 = xr[2048]; xgv3 = xr[3072];
  }

  // ---- round B: publish h0 (path-selected), flag fbase+2 ----
  if (act){
    float h0 = (dcur != 0.f) ? 0.f : ldsel(isf32, h0_p, (size_t)(rr0 + row)*HIDD + cc0 + col);
    unsigned short hu = f2b(h0);
    unsigned hv = (unsigned)hu | ((unsigned)(unsigned short)__shfl_down((int)hu, 1, 64) << 16);
    if ((tid & 1) == 0)
      st32p((unsigned*)&g_hp2[grp*8192 + shrd*128 + row*16 + col], hv, lcl);
  }
  __syncthreads();   // drains tracked stores
  if (tid == 0) st32p(&g_flags[fown], fbase + 2u, lcl);

  // preload w_hh K-quarter for all 4 gates
  const unsigned short* wbase = g_wbuf + OWHH;
  bf16x8 wreg[4][8];
#pragma unroll
  for (int g = 0; g < 4; g++)
#pragma unroll
    for (int i = 0; i < 8; i++)
      wreg[g][i] = *(const bf16x8*)&wbase[(size_t)(g*HIDD + cc0 + l16)*HIDD + wv*256 + i*32 + quad*8];

  // A-fragment addressing: rows l16<8 from staged tiles, rows >=8 from zero pad
  const unsigned a0   = (l16 < 8) ? (unsigned)(wv*2048 + (quad >> 1)*128 + l16*16 + (quad & 1)*8) : 8192u;
  const unsigned astp = (l16 < 8) ? 256u : 0u;
  const int fpoll = grp*64 + wv*16 + (ln & 15);

  const f32x4 zf = {0.f, 0.f, 0.f, 0.f};

#define MFMA_ITER(ii, NW)                                                        \
  {                                                                              \
    asm volatile("s_waitcnt vmcnt(" #NW ")" ::: "memory");                       \
    bf16x8 af = *(const bf16x8*)(sH + a0 + (ii)*astp);                           \
    _Pragma("unroll")                                                            \
    for (int g = 0; g < 4; g++)                                                  \
      acc[g] = __builtin_amdgcn_mfma_f32_16x16x32_bf16(af, wreg[g][ii],          \
                                                       acc[g], 0, 0, 0);         \
  }

  for (int s = 0; s < TSTEPS; s++){
    asm volatile("s_waitcnt vmcnt(0)" ::: "memory");

    // per-wave wait on 16 producer flags, bounded
    {
      const unsigned tgt = fbase + (unsigned)s + 2u;
      const unsigned long long tp = __builtin_amdgcn_s_memrealtime();
      unsigned it = 0;
      unsigned f = ld32p(&g_flags[fpoll], lcl);
      while (!__all((int)(f >= tgt))){
        if (((++it) & 255u) == 0u){
          unsigned a = __hip_atomic_load(&g_abort, __ATOMIC_RELAXED, __HIP_MEMORY_SCOPE_AGENT);
          if (a || (__builtin_amdgcn_s_memrealtime() - tp) > 400000ull){
            if (ln == 0) *(volatile int*)&s_abort = 1;
            break;   // fall through with garbage; exit at the uniform point below
          }
        }
        __builtin_amdgcn_s_sleep(1);
        f = ld32p(&g_flags[fpoll], lcl);
      }
    }
    asm volatile("s_waitcnt vmcnt(0)" ::: "memory");

    const unsigned short* hb = g_hp2 + (s & 1)*65536 + grp*8192;
    unsigned short*       hn = g_hp2 + ((s + 1) & 1)*65536 + grp*8192;

    // stage this wave's 4KB h K-quarter: 4 x 1KB direct-to-LDS loads
    {
      const unsigned short* src = hb + wv*2048 + ln*8;
      unsigned short* dstb = sH + wv*2048;
      if (lcl){
#pragma unroll
        for (int c2 = 0; c2 < 4; c2++) gld16s(src + c2*512, dstb + c2*512);
      } else {
#pragma unroll
        for (int c2 = 0; c2 < 4; c2++) gld16c(src + c2*512, dstb + c2*512);
      }
    }

    f32x4 acc[4];
#pragma unroll
    for (int g = 0; g < 4; g++) acc[g] = zf;

    MFMA_ITER(0, 3)
    MFMA_ITER(1, 3)
    MFMA_ITER(2, 2)
    MFMA_ITER(3, 2)
    MFMA_ITER(4, 1)
    MFMA_ITER(5, 1)
    MFMA_ITER(6, 0)
    MFMA_ITER(7, 0)

    if (quad < 2){
#pragma unroll
      for (int g = 0; g < 4; g++)
#pragma unroll
        for (int r = 0; r < 4; r++)
          sPf[wv*1024 + g*160 + (quad*4 + r)*20 + l16] = acc[g][r];
    }
    __syncthreads();

    if (act){
      float pg0 = 0.f, pg1 = 0.f, pg2 = 0.f, pg3 = 0.f;
#pragma unroll
      for (int w2 = 0; w2 < 4; w2++){
        const float* sb = &sPf[w2*1024 + row*20 + col];
        pg0 += sb[0];
        pg1 += sb[160];
        pg2 += sb[320];
        pg3 += sb[480];
      }
      float iv = sigm (pg0 + xgv0);
      float fv = sigm (pg1 + xgv1);
      float gv = tanh_f(pg2 + xgv2);
      float ov = sigm (pg3 + xgv3);
      float cp = (dcur != 0.f) ? 0.f : cst;
      float c  = fv*cp + iv*gv;
      float h  = ov * tanh_f(c);
      cst = c;
      if (s == TSTEPS-1){
        g_ht[(rr0 + row)*HIDD + cc0 + col] = h;
        g_ct[(rr0 + row)*HIDD + cc0 + col] = c;
      }
      unsigned short hu = f2b(h);
      unsigned hv = (unsigned)hu | ((unsigned)(unsigned short)__shfl_down((int)hu, 1, 64) << 16);
      unsigned hm = (dnxt != 0.f) ? 0u : hv;
      if ((tid & 1) == 0)
        st32p((unsigned*)&hn[shrd*128 + row*16 + col], hm, lcl);
      xgv0 = __builtin_bit_cast(float, hv);   // stash for hid2 store below
    }
    __syncthreads();   // uniform point: all waves see s_abort; drains stores
    if (*(volatile int*)&s_abort){
      if (tid == 0)
        __hip_atomic_store(&g_abort, 1u, __ATOMIC_RELAXED, __HIP_MEMORY_SCOPE_AGENT);
      return;          // safe kernel recomputes everything
    }
    if (tid == 0) st32p(&g_flags[fown], fbase + (unsigned)s + 3u, lcl);

    // off the critical path: blocked hidden store + next-step input prefetch
    if (act){
      const int token = s*BATCH + rr0 + row;
      if ((tid & 1) == 0)
        *(unsigned*)&g_hid2[(size_t)shrd*((size_t)TOK*16) + (size_t)token*16 + col] =
            __builtin_bit_cast(unsigned, xgv0);
      if (s + 1 < TSTEPS){
        const float* xr = &g_xgf[(size_t)((s+1)*BATCH + rr0 + row)*4096 + cc0 + col];
        xgv0 = xr[0]; xgv1 = xr[1024]; xgv2 = xr[2048]; xgv3 = xr[3072];
        dcur = dnxt;
        dnxt = (s + 2 < TSTEPS) ? ldsel(isf32, done_p, (size_t)(s+2)*BATCH + rr0 + row) : 0.f;
      }
    }
  }
#undef MFMA_ITER

  if (tid == 0)
    __hip_atomic_fetch_add(&g_done, 1u, __ATOMIC_RELAXED, __HIP_MEMORY_SCOPE_AGENT);
}

// ======================= SAFE LSTM scan (R3-verified, 256 WGs) =======================
// Runs the full scan unless lstm_scan_fast completed (g_done==512).
// Identical math/order to R3's 606us kernel; uses g_flags2 (disjoint epochs).
__global__ __launch_bounds__(256, 1) void lstm_scan_safe(
    const void* __restrict__ done_p,
    const void* __restrict__ h0_p,
    const void* __restrict__ c0_p)
{
  if (__hip_atomic_load(&g_done, __ATOMIC_RELAXED, __HIP_MEMORY_SCOPE_AGENT) >= 512u)
    return;   // fast path already produced g_hid2/g_ht/g_ct

  __shared__ __align__(16) unsigned short sH[16384];
  float* sPf = (float*)sH;

  const int tid  = threadIdx.x;
  const int wv   = tid >> 6, ln = tid & 63;
  const int quad = ln >> 4, l16 = ln & 15;
  const int cbid = blockIdx.x;
  const int grp  = cbid >> 6;          // batch-group: rows [grp*16, +16)
  const int shrd = cbid & 63;          // col-shard:  cols [shrd*16, +16)
  const int rr0  = grp * 16;
  const int cc0  = shrd * 16;
  const int row  = tid >> 4;
  const int col  = tid & 15;
  const bool isf32 = (g_isf32 != 0);
  const unsigned fbase = g_fepoch;
  const int fidx = grp*64 + wv*16 + (ln & 15);

  float cst = ldsel(isf32, c0_p, (size_t)(rr0 + row)*HIDD + cc0 + col);

  {
    float d0 = ldsel(isf32, done_p, rr0 + row);
    float h0 = (d0 != 0.f) ? 0.f : ldsel(isf32, h0_p, (size_t)(rr0 + row)*HIDD + cc0 + col);
    unsigned short hu = f2b(h0);
    unsigned hv = (unsigned)hu | ((unsigned)(unsigned short)__shfl_down((int)hu, 1, 64) << 16);
    if ((ln & 1) == 0){
      unsigned* hp = (unsigned*)&g_hp2[grp*16384 + shrd*256 + row*16 + col];
      __hip_atomic_store(hp, hv, __ATOMIC_RELAXED, __HIP_MEMORY_SCOPE_AGENT);
    }
  }

  const unsigned short* wbase = g_wbuf + OWHH;
  bf16x8 wreg[4][8];
#pragma unroll
  for (int g = 0; g < 4; g++)
#pragma unroll
    for (int i = 0; i < 8; i++)
      wreg[g][i] = *(const bf16x8*)&wbase[(size_t)(g*HIDD + cc0 + l16)*HIDD + wv*256 + i*32 + quad*8];

  float xgv0, xgv1, xgv2, xgv3;
  {
    const float* xr = &g_xgf[(size_t)(rr0 + row)*4096 + cc0 + col];
    xgv0 = xr[0]; xgv1 = xr[1024]; xgv2 = xr[2048]; xgv3 = xr[3072];
  }
  float dcur = ldsel(isf32, done_p, rr0 + row);
  float dnxt = ldsel(isf32, done_p, BATCH + rr0 + row);

  __syncthreads();
  if (tid == 0)
    __hip_atomic_store(&g_flags2[cbid], fbase + 1, __ATOMIC_RELAXED, __HIP_MEMORY_SCOPE_AGENT);

  const f32x4 zf = {0.f, 0.f, 0.f, 0.f};

#define MFMA_ITER(ii, NW)                                                        \
  {                                                                              \
    asm volatile("s_waitcnt vmcnt(" #NW ")" ::: "memory");                       \
    bf16x8 af = *(const bf16x8*)(hq + (ii)*512);                                 \
    _Pragma("unroll")                                                            \
    for (int g = 0; g < 4; g++)                                                  \
      acc[g] = __builtin_amdgcn_mfma_f32_16x16x32_bf16(af, wreg[g][ii],          \
                                                       acc[g], 0, 0, 0);         \
  }

  for (int s = 0; s < TSTEPS; s++){
    asm volatile("s_waitcnt vmcnt(0)" ::: "memory");
    {
      const unsigned tgt = fbase + (unsigned)s + 1u;
      unsigned f = __hip_atomic_load(&g_flags2[fidx], __ATOMIC_RELAXED, __HIP_MEMORY_SCOPE_AGENT);
      while (!__all((int)(f >= tgt))){
        __builtin_amdgcn_s_sleep(1);
        f = __hip_atomic_load(&g_flags2[fidx], __ATOMIC_RELAXED, __HIP_MEMORY_SCOPE_AGENT);
      }
    }
    asm volatile("s_waitcnt vmcnt(0)" ::: "memory");

    const unsigned short* hb = g_hp2 + (s & 1)*65536 + grp*16384;
    unsigned short*       hn = g_hp2 + ((s + 1) & 1)*65536 + grp*16384;

    {
      const unsigned short* src = hb + wv*4096 + ln*8;
      unsigned short* dstb = sH + wv*4096;
#pragma unroll
      for (int c2 = 0; c2 < 8; c2++)
        gld16c(src + c2*512, dstb + c2*512);
    }

    const unsigned short* hq = sH + wv*4096 + (quad >> 1)*256 + l16*16 + (quad & 1)*8;
    f32x4 acc[4];
#pragma unroll
    for (int g = 0; g < 4; g++) acc[g] = zf;

    MFMA_ITER(0, 7)
    MFMA_ITER(1, 6)
    MFMA_ITER(2, 5)
    MFMA_ITER(3, 4)
    MFMA_ITER(4, 3)
    MFMA_ITER(5, 2)
    MFMA_ITER(6, 1)
    MFMA_ITER(7, 0)

#pragma unroll
    for (int g = 0; g < 4; g++)
#pragma unroll
      for (int r = 0; r < 4; r++)
        sPf[wv*2048 + g*320 + (quad*4 + r)*20 + l16] = acc[g][r];
    __syncthreads();

    float pg0 = 0.f, pg1 = 0.f, pg2 = 0.f, pg3 = 0.f;
#pragma unroll
    for (int w2 = 0; w2 < 4; w2++){
      const float* sb = &sPf[w2*2048 + row*20 + col];
      pg0 += sb[0];
      pg1 += sb[320];
      pg2 += sb[640];
      pg3 += sb[960];
    }
    const bool last = (s == TSTEPS-1);
    float iv = sigm (pg0 + xgv0);
    float fv = sigm (pg1 + xgv1);
    float gv = tanh_f(pg2 + xgv2);
    float ov = sigm (pg3 + xgv3);
    float cp = (dcur != 0.f) ? 0.f : cst;
    float c  = fv*cp + iv*gv;
    float h  = ov * tanh_f(c);
    cst = c;
    if (last){
      g_ht[(rr0 + row)*HIDD + cc0 + col] = h;
      g_ct[(rr0 + row)*HIDD + cc0 + col] = c;
    }
    unsigned short hu = f2b(h);
    unsigned hv = (unsigned)hu | ((unsigned)(unsigned short)__shfl_down((int)hu, 1, 64) << 16);
    unsigned hm = (dnxt != 0.f) ? 0u : hv;
    if ((ln & 1) == 0){
      unsigned* hnp = (unsigned*)&hn[shrd*256 + row*16 + col];
      __hip_atomic_store(hnp, hm, __ATOMIC_RELAXED, __HIP_MEMORY_SCOPE_AGENT);
    }

    __syncthreads();
    if (tid == 0)
      __hip_atomic_store(&g_flags2[cbid], fbase + (unsigned)s + 2u, __ATOMIC_RELAXED, __HIP_MEMORY_SCOPE_AGENT);

    const int token = s*BATCH + rr0 + row;
    if ((ln & 1) == 0)
      *(unsigned*)&g_hid2[(size_t)shrd*((size_t)TOK*16) + (size_t)token*16 + col] = hv;

    if (s + 1 < TSTEPS){
      const float* xr = &g_xgf[(size_t)((s+1)*BATCH + rr0 + row)*4096 + cc0 + col];
      xgv0 = xr[0]; xgv1 = xr[1024]; xgv2 = xr[2048]; xgv3 = xr[3072];
      dcur = dnxt;
      dnxt = (s + 2 < TSTEPS) ? ldsel(isf32, done_p, (size_t)(s+2)*BATCH + rr0 + row) : 0.f;
    }
  }
#undef MFMA_ITER
}

// ---------------- FINALIZE: only writer of d_out (fp32), value head inline --------
__global__ __launch_bounds__(256) void finalize(
    const int* __restrict__ action, const void* __restrict__ b_cr2,
    float* __restrict__ dout)
{
  int row = blockIdx.x*4 + (threadIdx.x >> 6);
  int ln  = threadIdx.x & 63;
  size_t base = (size_t)row * NACT;
  float l0 = b2f(g_aco[base+ln])    + b2f(g_cwo[base+ln])   *b2f(g_covo[base+ln]);
  float l1 = b2f(g_aco[base+64+ln]) + b2f(g_cwo[base+64+ln])*b2f(g_covo[base+64+ln]);
  float mx = fmaxf(l0, l1);
  for (int o = 32; o; o >>= 1) mx = fmaxf(mx, __shfl_xor(mx, o, 64));
  float e0 = __expf(l0 - mx), e1 = __expf(l1 - mx);
  float sm = e0 + e1;
  for (int o = 32; o; o >>= 1) sm += __shfl_xor(sm, o, 64);
  float inv = 1.f/sm, ls = __logf(sm);
  float p0 = e0*inv, p1 = e1*inv;
  float lp0 = l0 - mx - ls, lp1 = l1 - mx - ls;
  dout[O_PROBS + base + ln]      = p0;
  dout[O_PROBS + base + 64 + ln] = p1;
  float ent = -(p0*lp0 + p1*lp1);
  for (int o = 32; o; o >>= 1) ent += __shfl_xor(ent, o, 64);
  int a = action[row];
  float lpa = (a == ln) ? lp0 : (a == ln + 64) ? lp1 : 0.f;
  for (int o = 32; o; o >>= 1) lpa += __shfl_xor(lpa, o, 64);

  // value head: wave-per-row dot over cr slice of t3
  const unsigned short* Acr = g_t3 + 2048;
  const unsigned short* wcr = g_wbuf + OCRW2;
  float sv = 0.f;
  for (int k = ln*8; k < HIDD; k += 512){
    bf16x8 av = *(const bf16x8*)&Acr[(size_t)row*3072 + k];
    bf16x8 wv8 = *(const bf16x8*)&wcr[k];
#pragma unroll
    for (int j = 0; j < 8; j++) sv += b2f((unsigned short)av[j]) * b2f((unsigned short)wv8[j]);
  }
  for (int o = 32; o; o >>= 1) sv += __shfl_xor(sv, o, 64);

  if (ln == 0){
    dout[O_LOGPA + row] = lpa;
    dout[O_ENT   + row] = ent;
    dout[O_VAL   + row] = sv + ldmix(b_cr2, 0);
  }
  int gtid = blockIdx.x*256 + threadIdx.x;
  if (gtid < BATCH*HIDD){
    dout[O_HT + gtid] = g_ht[gtid];
    dout[O_CT + gtid] = g_ct[gtid];
  }
}

// ---------------- host ----------------
extern "C" void kernel_launch(void* const* d_in, const int* in_sizes, int n_in,
                              void* d_out, int out_size, void* d_ws, size_t ws_size,
                              hipStream_t stream)
{
  (void)in_sizes; (void)n_in; (void)out_size; (void)d_ws; (void)ws_size;
  float* dout = (float*)d_out;

  hipLaunchKernelGGL(detect_dtype, dim3(1), dim3(256), 0, stream,
                     (const unsigned short*)d_in[0]);

  hipLaunchKernelGGL(cvt_all, dim3(512, 14), dim3(256), 0, stream,
                     d_in[0], d_in[2], d_in[6], d_in[8], d_in[10], d_in[11],
                     d_in[18], d_in[26], d_in[14], d_in[20], d_in[28],
                     d_in[22], d_in[24], d_in[16]);

  auto gemm = [&](int a_id, int lda, int ablk, int w_id, int K,
                  const void* b1, const void* b2, const void* b3, int bmode,
                  int c_id, int ldc, int N, int act, int cmode){
    hipLaunchKernelGGL(gemm_bt, dim3(N/128, TOK/128), dim3(256), 0, stream,
                       a_id, lda, ablk, w_id, K, b1, b2, b3, bmode,
                       c_id, ldc, act, cmode);
  };

  // perception MLP + hoisted input-gate GEMM
  gemm(11, OBSD, 0, 13, OBSD, d_in[7],  nullptr, nullptr, 0, 1, HIDD,   HIDD,   1, 0);
  gemm(1,  HIDD, 0, 14, HIDD, d_in[9],  nullptr, nullptr, 0, 2, HIDD,   HIDD,   1, 0);
  gemm(2,  HIDD, 0, 15, HIDD, d_in[12], d_in[13], nullptr, 0, 8, 4*HIDD, 4*HIDD, 0, 1);

  // LSTM scan: bounded-liveness fast attempt (512 WGs, XCD-local protocol),
  // then the R3-proven safe kernel which no-ops iff the fast path completed.
  hipLaunchKernelGGL(lstm_scan_fast, dim3(512), dim3(256), 0, stream,
                     d_in[1], d_in[3], d_in[4]);
  hipLaunchKernelGGL(lstm_scan_safe, dim3(256), dim3(256), 0, stream,
                     d_in[1], d_in[3], d_in[4]);

  // fused head hidden GEMM: t3 = tanh(hidden @ [ac|cw|cr]w1^T + b), N=3072, blocked A
  gemm(3, 3072, 1, 17, HIDD, d_in[19], d_in[27], d_in[15], 1, 4, 3*HIDD, 3*HIDD, 1, 0);
  // coverage perception GEMM (feeds covo)
  gemm(12, NACT, 0, 22, NACT, d_in[23], nullptr, nullptr, 0, 1, HIDD, HIDD, 1, 0);
  // fused output heads: aco | cwo | covo in one launch
  hipLaunchKernelGGL(gemm_heads, dim3(3, TOK/128), dim3(256), 0, stream,
                     d_in[21], d_in[29], d_in[25]);

  // single final writer of d_out (value head folded in)
  hipLaunchKernelGGL(finalize, dim3(TOK/4), dim3(256), 0, stream,
                     (const int*)d_in[5], d_in[17], dout);
}